// Round 15
// baseline (582.209 us; speedup 1.0000x reference)
//
#include <hip/hip_runtime.h>

// FiLM LSTM, R15: R13 structure x 2 batches per block (TLP overlap).
//   128 blocks x 512 thr (8 waves). Waves 0-3 = batch 2b, waves 4-7 = 2b+1:
//   two independent R13 recurrences share the block barrier; each SIMD holds
//   2 waves (one per batch) whose serial-chain latencies hide each other.
//   Per group: wave wl owns units 16wl..16wl+15; xz in registers (reg r of
//   kgrp g = xz[step 4g+r]); kgrp g active for steps 4g..4g+3; c handoff via
//   LDS once per 4 steps. NK=-log2(e) folded into W,U,bias:
//   sigma(z)=rcp(1+exp2(z')). Per-step sync: lgkmcnt(0) + raw s_barrier.

typedef _Float16 f16;
typedef f16  half8 __attribute__((ext_vector_type(8)));
typedef __fp16 fp16x2 __attribute__((ext_vector_type(2)));
typedef float f32x4 __attribute__((ext_vector_type(4)));

constexpr int Bsz = 256;
constexpr int Tn  = 2048;
constexpr int Dn  = 64;
constexpr int G4  = 256;

__global__ __launch_bounds__(512, 1) void lstm_film_mfma(
    const float* __restrict__ x,     // [B,T,64] f32
    const float* __restrict__ W,     // [64,256]
    const float* __restrict__ U,     // [64,256]
    const float* __restrict__ bias,  // [256]
    const float* __restrict__ wg, const float* __restrict__ bgam,
    const float* __restrict__ wb, const float* __restrict__ bbet,
    float* __restrict__ out)         // gamma[256] then beta[256]
{
    __shared__ __align__(16) char hbuf[2][2][128];   // [group][parity][64 f16]
    __shared__ __align__(16) float c_lds[2][64];     // [group][unit]

    const int tid  = threadIdx.x;
    const int w    = tid >> 6;        // 0..7
    const int grp  = w >> 2;          // batch group 0/1
    const int wl   = w & 3;           // wave within group
    const int l    = tid & 63;
    const int lrow = l & 15;
    const int kgrp = l >> 4;

    const float NK = -1.44269504f;

    // B fragments (pre-scaled): kf 0,1 = U k 0-31/32-63; kf 2,3 = W
    half8 Bf[4][4];
#pragma unroll
    for (int kf = 0; kf < 4; ++kf) {
        const float* M = (kf < 2) ? U : W;
        const int krow0 = (kf & 1) * 32 + kgrp * 8;
#pragma unroll
        for (int q = 0; q < 4; ++q) {
            const int col = q * 64 + wl * 16 + lrow;
#pragma unroll
            for (int j = 0; j < 8; ++j)
                Bf[kf][q][j] = (f16)(M[(krow0 + j) * G4 + col] * NK);
        }
    }
    f32x4 bqv[4];
#pragma unroll
    for (int q = 0; q < 4; ++q) {
        const float b = bias[q * 64 + wl * 16 + lrow] * NK;
        bqv[q] = f32x4{b, b, b, b};
    }
    const f32x4 ZV = {0.f, 0.f, 0.f, 0.f};

    if (tid < 32) ((uint4*)hbuf)[tid] = uint4{0, 0, 0, 0};   // 512 B
    if (tid < 128) ((float*)c_lds)[tid] = 0.0f;
    float c = 0.0f;

    const int batch = blockIdx.x * 2 + grp;
    const float* xlane = x + ((size_t)batch * Tn + lrow) * Dn + kgrp * 8;
    const char* hb0 = hbuf[grp][0];
    const char* hb1 = hbuf[grp][1];
    const int rdH0 = kgrp * 16;
    const int rdH1 = kgrp * 16 + 64;
    const int wrH  = (wl * 16 + lrow) * 2;
    float* cg = c_lds[grp];
    const int cidx = wl * 16 + lrow;

    const float wgj = wg[l], wbj = wb[l];
    const float bg0 = bgam[0], bb0 = bbet[0];

    __syncthreads();   // zeros visible

    union U16 { fp16x2 p[4]; half8 h8; };
    U16 u0, u1;
    float4 R[4];
    f32x4 qA0, qA1, qA2, qA3, qB0, qB1, qB2, qB3;

#define XL(T0) do { const float* p_ = xlane + (size_t)(T0) * Dn;             \
        R[0] = *(const float4*)(p_);      R[1] = *(const float4*)(p_ + 4);   \
        R[2] = *(const float4*)(p_ + 32); R[3] = *(const float4*)(p_ + 36);  \
    } while (0)

#define CVT0 do {                                                            \
        u0.p[0] = __builtin_amdgcn_cvt_pkrtz(R[0].x, R[0].y);                \
        u0.p[1] = __builtin_amdgcn_cvt_pkrtz(R[0].z, R[0].w);                \
        u0.p[2] = __builtin_amdgcn_cvt_pkrtz(R[1].x, R[1].y);                \
        u0.p[3] = __builtin_amdgcn_cvt_pkrtz(R[1].z, R[1].w); } while (0)
#define CVT1 do {                                                            \
        u1.p[0] = __builtin_amdgcn_cvt_pkrtz(R[2].x, R[2].y);                \
        u1.p[1] = __builtin_amdgcn_cvt_pkrtz(R[2].z, R[2].w);                \
        u1.p[2] = __builtin_amdgcn_cvt_pkrtz(R[3].x, R[3].y);                \
        u1.p[3] = __builtin_amdgcn_cvt_pkrtz(R[3].z, R[3].w); } while (0)

#define MFM __builtin_amdgcn_mfma_f32_16x16x32_f16

#define HSTEP(S, Q, ...) do {                                                \
        asm volatile("s_waitcnt lgkmcnt(0)" ::: "memory");                   \
        __builtin_amdgcn_s_barrier();                                        \
        asm volatile("" ::: "memory");                                       \
        const char* hb_ = ((S) & 1) ? hb1 : hb0;                             \
        half8 ah0 = *(const half8*)(hb_ + rdH0);                             \
        half8 ah1 = *(const half8*)(hb_ + rdH1);                             \
        if (((S) & 3) == 0) c = cg[cidx];                                    \
        f32x4 a0 = MFM(ah0, Bf[0][0], bqv[0], 0, 0, 0);                      \
        f32x4 a1 = MFM(ah0, Bf[0][1], bqv[1], 0, 0, 0);                      \
        f32x4 a2 = MFM(ah0, Bf[0][2], bqv[2], 0, 0, 0);                      \
        f32x4 a3 = MFM(ah0, Bf[0][3], bqv[3], 0, 0, 0);                      \
        a0 = MFM(ah1, Bf[1][0], a0, 0, 0, 0);                                \
        a1 = MFM(ah1, Bf[1][1], a1, 0, 0, 0);                                \
        a2 = MFM(ah1, Bf[1][2], a2, 0, 0, 0);                                \
        a3 = MFM(ah1, Bf[1][3], a3, 0, 0, 0);                                \
        __VA_ARGS__                                                          \
        const float zi = Q##0[(S) & 3] + a0[(S) & 3];                        \
        const float zf = Q##1[(S) & 3] + a1[(S) & 3];                        \
        const float zg = Q##2[(S) & 3] + a2[(S) & 3];                        \
        const float zo = Q##3[(S) & 3] + a3[(S) & 3];                        \
        const float ei = __builtin_amdgcn_exp2f(zi);                         \
        const float ef = __builtin_amdgcn_exp2f(zf);                         \
        const float eg = __builtin_amdgcn_exp2f(zg);                         \
        const float eo = __builtin_amdgcn_exp2f(zo);                         \
        const float sf  = __builtin_amdgcn_rcpf(1.0f + ef);                  \
        const float sig = __builtin_amdgcn_rcpf((1.0f + ei) * (1.0f + eg));  \
        c = fmaf(sf, c, sig);                                                \
        const float ec = __builtin_amdgcn_exp2f(c * NK);                     \
        const float hh = __builtin_amdgcn_rcpf((1.0f + eo) * (1.0f + ec));   \
        if (kgrp == ((S) >> 2)) {                                            \
            char* ho_ = (char*)(((S) & 1) ? hb0 : hb1);                      \
            *(f16*)(ho_ + wrH) = (f16)hh;                                    \
            if (((S) & 3) == 3) cg[cidx] = c;                                \
        }                                                                    \
    } while (0)

#define BLOCK16(QC, QN, TNX)                                                 \
        HSTEP(0, QC);  HSTEP(1, QC);  HSTEP(2, QC);  HSTEP(3, QC);           \
        HSTEP(4, QC);  HSTEP(5, QC);  HSTEP(6, QC);  HSTEP(7, QC);           \
        HSTEP(8, QC,  CVT0; QN##0 = MFM(u0.h8, Bf[2][0], ZV, 0, 0, 0); );    \
        HSTEP(9, QC,        QN##1 = MFM(u0.h8, Bf[2][1], ZV, 0, 0, 0); );    \
        HSTEP(10, QC,       QN##2 = MFM(u0.h8, Bf[2][2], ZV, 0, 0, 0); );    \
        HSTEP(11, QC,       QN##3 = MFM(u0.h8, Bf[2][3], ZV, 0, 0, 0); );    \
        HSTEP(12, QC, CVT1; QN##0 = MFM(u1.h8, Bf[3][0], QN##0, 0, 0, 0); ); \
        HSTEP(13, QC,       QN##1 = MFM(u1.h8, Bf[3][1], QN##1, 0, 0, 0);    \
                            XL(TNX); );                                      \
        HSTEP(14, QC,       QN##2 = MFM(u1.h8, Bf[3][2], QN##2, 0, 0, 0); ); \
        HSTEP(15, QC,       QN##3 = MFM(u1.h8, Bf[3][3], QN##3, 0, 0, 0); );

    // prologue: qA = xz block 0; R <- block 1
    XL(0);
    CVT0; CVT1;
    qA0 = MFM(u0.h8, Bf[2][0], ZV, 0, 0, 0);
    qA1 = MFM(u0.h8, Bf[2][1], ZV, 0, 0, 0);
    qA2 = MFM(u0.h8, Bf[2][2], ZV, 0, 0, 0);
    qA3 = MFM(u0.h8, Bf[2][3], ZV, 0, 0, 0);
    qA0 = MFM(u1.h8, Bf[3][0], qA0, 0, 0, 0);
    qA1 = MFM(u1.h8, Bf[3][1], qA1, 0, 0, 0);
    qA2 = MFM(u1.h8, Bf[3][2], qA2, 0, 0, 0);
    qA3 = MFM(u1.h8, Bf[3][3], qA3, 0, 0, 0);
    XL(16);

    for (int tb = 0; tb < Tn / 16; tb += 2) {
        int t2 = (tb + 2) * 16; if (t2 > Tn - 16) t2 = Tn - 16;
        int t3 = (tb + 3) * 16; if (t3 > Tn - 16) t3 = Tn - 16;
        BLOCK16(qA, qB, t2)
        BLOCK16(qB, qA, t3)
    }
#undef BLOCK16
#undef HSTEP
#undef MFM
#undef CVT0
#undef CVT1
#undef XL

    __syncthreads();   // final h (step 2047 wrote parity-0) visible

    // heads: wave 0 of each group; lane l = unit l
    if (wl == 0) {
        const float hv = (float)*(const f16*)(hbuf[grp][0] + l * 2);
        float vg = hv * wgj, vb = hv * wbj;
#pragma unroll
        for (int off = 32; off > 0; off >>= 1) {
            vg += __shfl_xor(vg, off, 64);
            vb += __shfl_xor(vb, off, 64);
        }
        if (l == 0) {
            out[batch]       = vg + bg0;
            out[Bsz + batch] = vb + bb0;
        }
    }
}

extern "C" void kernel_launch(void* const* d_in, const int* in_sizes, int n_in,
                              void* d_out, int out_size, void* d_ws, size_t ws_size,
                              hipStream_t stream) {
    const float* x    = (const float*)d_in[0];
    const float* W    = (const float*)d_in[2];
    const float* U    = (const float*)d_in[3];
    const float* bias = (const float*)d_in[4];
    const float* wg   = (const float*)d_in[5];
    const float* bgam = (const float*)d_in[6];
    const float* wb   = (const float*)d_in[7];
    const float* bbet = (const float*)d_in[8];
    float* out = (float*)d_out;

    lstm_film_mfma<<<Bsz / 2, 512, 0, stream>>>(x, W, U, bias,
                                                wg, bgam, wb, bbet, out);
}

// Round 16
// 428.917 us; speedup vs baseline: 1.3574x; 1.3574x over previous
//
#include <hip/hip_runtime.h>

// FiLM LSTM, R16: R13 + MFMA-C-in z-fusion.
//   256 blocks (1 batch/CU) x 256 thr (4 waves). Wave w owns units 16w..16w+15.
//   xz (x@W + bias, M-rows = 16 timesteps) lives in REGISTERS, seeded with
//   bias-splat: reg r of kgrp g = xz[step 4g+r]. Per step, the h-MFMA chain
//   uses C-in = Q (the xz accumulator) so z = a[S&3] directly -- no VALU adds.
//   kgrp g active for steps 4g..4g+3 (masked h/c writes); c handoff via LDS
//   once per 4 steps (read hoisted above the h ds_reads).
//   NK=-log2(e) folded into W,U,bias: sigma(z)=rcp(1+exp2(z')).
//   Per-step sync: s_waitcnt lgkmcnt(0) + raw s_barrier.

typedef _Float16 f16;
typedef f16  half8 __attribute__((ext_vector_type(8)));
typedef __fp16 fp16x2 __attribute__((ext_vector_type(2)));
typedef float f32x4 __attribute__((ext_vector_type(4)));

constexpr int Bsz = 256;
constexpr int Tn  = 2048;
constexpr int Dn  = 64;
constexpr int G4  = 256;

__global__ __launch_bounds__(256, 1) void lstm_film_mfma(
    const float* __restrict__ x,     // [B,T,64] f32
    const float* __restrict__ W,     // [64,256]
    const float* __restrict__ U,     // [64,256]
    const float* __restrict__ bias,  // [256]
    const float* __restrict__ wg, const float* __restrict__ bgam,
    const float* __restrict__ wb, const float* __restrict__ bbet,
    float* __restrict__ out)         // gamma[256] then beta[256]
{
    __shared__ __align__(16) char hbuf[2][128];   // h double buffer
    __shared__ __align__(16) float c_lds[64];     // c handoff

    const int tid  = threadIdx.x;
    const int w    = tid >> 6;
    const int l    = tid & 63;
    const int lrow = l & 15;
    const int kgrp = l >> 4;

    const float NK = -1.44269504f;

    // B fragments (pre-scaled): kf 0,1 = U k 0-31/32-63; kf 2,3 = W
    half8 Bf[4][4];
#pragma unroll
    for (int kf = 0; kf < 4; ++kf) {
        const float* M = (kf < 2) ? U : W;
        const int krow0 = (kf & 1) * 32 + kgrp * 8;
#pragma unroll
        for (int q = 0; q < 4; ++q) {
            const int col = q * 64 + w * 16 + lrow;
#pragma unroll
            for (int j = 0; j < 8; ++j)
                Bf[kf][q][j] = (f16)(M[(krow0 + j) * G4 + col] * NK);
        }
    }
    f32x4 bqv[4];
#pragma unroll
    for (int q = 0; q < 4; ++q) {
        const float b = bias[q * 64 + w * 16 + lrow] * NK;
        bqv[q] = f32x4{b, b, b, b};
    }

    if (tid < 16) ((uint4*)hbuf)[tid] = uint4{0, 0, 0, 0};
    if (tid < 64) c_lds[tid] = 0.0f;
    float c = 0.0f;

    const float* xlane = x + ((size_t)blockIdx.x * Tn + lrow) * Dn + kgrp * 8;
    const int rdH0 = kgrp * 16;
    const int rdH1 = kgrp * 16 + 64;
    const int wrH  = (w * 16 + lrow) * 2;
    const int cidx = w * 16 + lrow;

    const float wgj = wg[l], wbj = wb[l];
    const float bg0 = bgam[0], bb0 = bbet[0];

    __syncthreads();   // zeros visible

    union U16 { fp16x2 p[4]; half8 h8; };
    U16 u0, u1;
    float4 R[4];
    f32x4 qA0, qA1, qA2, qA3, qB0, qB1, qB2, qB3;

#define XL(T0) do { const float* p_ = xlane + (size_t)(T0) * Dn;             \
        R[0] = *(const float4*)(p_);      R[1] = *(const float4*)(p_ + 4);   \
        R[2] = *(const float4*)(p_ + 32); R[3] = *(const float4*)(p_ + 36);  \
    } while (0)

#define CVT0 do {                                                            \
        u0.p[0] = __builtin_amdgcn_cvt_pkrtz(R[0].x, R[0].y);                \
        u0.p[1] = __builtin_amdgcn_cvt_pkrtz(R[0].z, R[0].w);                \
        u0.p[2] = __builtin_amdgcn_cvt_pkrtz(R[1].x, R[1].y);                \
        u0.p[3] = __builtin_amdgcn_cvt_pkrtz(R[1].z, R[1].w); } while (0)
#define CVT1 do {                                                            \
        u1.p[0] = __builtin_amdgcn_cvt_pkrtz(R[2].x, R[2].y);                \
        u1.p[1] = __builtin_amdgcn_cvt_pkrtz(R[2].z, R[2].w);                \
        u1.p[2] = __builtin_amdgcn_cvt_pkrtz(R[3].x, R[3].y);                \
        u1.p[3] = __builtin_amdgcn_cvt_pkrtz(R[3].z, R[3].w); } while (0)

#define MFM __builtin_amdgcn_mfma_f32_16x16x32_f16

    // __VA_ARGS__ = injected work, placed between MFMA issue and extraction
#define HSTEP(S, Q, ...) do {                                                \
        asm volatile("s_waitcnt lgkmcnt(0)" ::: "memory");                   \
        __builtin_amdgcn_s_barrier();                                        \
        asm volatile("" ::: "memory");                                       \
        if (((S) & 3) == 0) c = c_lds[cidx];                                 \
        const char* hb_ = hbuf[(S) & 1];                                     \
        half8 ah0 = *(const half8*)(hb_ + rdH0);                             \
        half8 ah1 = *(const half8*)(hb_ + rdH1);                             \
        /* C-in = Q (xz accumulator incl. bias): z = a[S&3] directly */      \
        f32x4 a0 = MFM(ah0, Bf[0][0], Q##0, 0, 0, 0);                        \
        f32x4 a1 = MFM(ah0, Bf[0][1], Q##1, 0, 0, 0);                        \
        f32x4 a2 = MFM(ah0, Bf[0][2], Q##2, 0, 0, 0);                        \
        f32x4 a3 = MFM(ah0, Bf[0][3], Q##3, 0, 0, 0);                        \
        a0 = MFM(ah1, Bf[1][0], a0, 0, 0, 0);                                \
        a1 = MFM(ah1, Bf[1][1], a1, 0, 0, 0);                                \
        a2 = MFM(ah1, Bf[1][2], a2, 0, 0, 0);                                \
        a3 = MFM(ah1, Bf[1][3], a3, 0, 0, 0);                                \
        __VA_ARGS__                                                          \
        const float ei = __builtin_amdgcn_exp2f(a0[(S) & 3]);                \
        const float ef = __builtin_amdgcn_exp2f(a1[(S) & 3]);                \
        const float eg = __builtin_amdgcn_exp2f(a2[(S) & 3]);                \
        const float eo = __builtin_amdgcn_exp2f(a3[(S) & 3]);                \
        const float sf  = __builtin_amdgcn_rcpf(1.0f + ef);                  \
        const float sig = __builtin_amdgcn_rcpf((1.0f + ei) * (1.0f + eg));  \
        c = fmaf(sf, c, sig);                                                \
        const float ec = __builtin_amdgcn_exp2f(c * NK);                     \
        const float hh = __builtin_amdgcn_rcpf((1.0f + eo) * (1.0f + ec));   \
        if (kgrp == ((S) >> 2)) {                                            \
            *(f16*)(hbuf[((S) & 1) ^ 1] + wrH) = (f16)hh;                    \
            if (((S) & 3) == 3) c_lds[cidx] = c;                             \
        }                                                                    \
    } while (0)

#define BLOCK16(QC, QN, TNX)                                                 \
        HSTEP(0, QC);  HSTEP(1, QC);  HSTEP(2, QC);  HSTEP(3, QC);           \
        HSTEP(4, QC);  HSTEP(5, QC);  HSTEP(6, QC);  HSTEP(7, QC);           \
        HSTEP(8, QC,  CVT0; QN##0 = MFM(u0.h8, Bf[2][0], bqv[0], 0, 0, 0); );\
        HSTEP(9, QC,        QN##1 = MFM(u0.h8, Bf[2][1], bqv[1], 0, 0, 0); );\
        HSTEP(10, QC,       QN##2 = MFM(u0.h8, Bf[2][2], bqv[2], 0, 0, 0); );\
        HSTEP(11, QC,       QN##3 = MFM(u0.h8, Bf[2][3], bqv[3], 0, 0, 0); );\
        HSTEP(12, QC, CVT1; QN##0 = MFM(u1.h8, Bf[3][0], QN##0, 0, 0, 0); ); \
        HSTEP(13, QC,       QN##1 = MFM(u1.h8, Bf[3][1], QN##1, 0, 0, 0);    \
                            XL(TNX); );                                      \
        HSTEP(14, QC,       QN##2 = MFM(u1.h8, Bf[3][2], QN##2, 0, 0, 0); ); \
        HSTEP(15, QC,       QN##3 = MFM(u1.h8, Bf[3][3], QN##3, 0, 0, 0); );

    // prologue: qA = xz block 0 (bias-seeded); R <- block 1
    XL(0);
    CVT0; CVT1;
    qA0 = MFM(u0.h8, Bf[2][0], bqv[0], 0, 0, 0);
    qA1 = MFM(u0.h8, Bf[2][1], bqv[1], 0, 0, 0);
    qA2 = MFM(u0.h8, Bf[2][2], bqv[2], 0, 0, 0);
    qA3 = MFM(u0.h8, Bf[2][3], bqv[3], 0, 0, 0);
    qA0 = MFM(u1.h8, Bf[3][0], qA0, 0, 0, 0);
    qA1 = MFM(u1.h8, Bf[3][1], qA1, 0, 0, 0);
    qA2 = MFM(u1.h8, Bf[3][2], qA2, 0, 0, 0);
    qA3 = MFM(u1.h8, Bf[3][3], qA3, 0, 0, 0);
    XL(16);

    for (int tb = 0; tb < Tn / 16; tb += 2) {
        int t2 = (tb + 2) * 16; if (t2 > Tn - 16) t2 = Tn - 16;
        int t3 = (tb + 3) * 16; if (t3 > Tn - 16) t3 = Tn - 16;
        BLOCK16(qA, qB, t2)
        BLOCK16(qB, qA, t3)
    }
#undef BLOCK16
#undef HSTEP
#undef MFM
#undef CVT0
#undef CVT1
#undef XL

    __syncthreads();   // final h (step 2047 wrote hbuf[0]) visible

    // heads: wave 0; lane l = unit l
    if (w == 0) {
        const float hv = (float)*(const f16*)(hbuf[0] + l * 2);
        float vg = hv * wgj, vb = hv * wbj;
#pragma unroll
        for (int off = 32; off > 0; off >>= 1) {
            vg += __shfl_xor(vg, off, 64);
            vb += __shfl_xor(vb, off, 64);
        }
        if (l == 0) {
            out[blockIdx.x]       = vg + bg0;
            out[Bsz + blockIdx.x] = vb + bb0;
        }
    }
}

extern "C" void kernel_launch(void* const* d_in, const int* in_sizes, int n_in,
                              void* d_out, int out_size, void* d_ws, size_t ws_size,
                              hipStream_t stream) {
    const float* x    = (const float*)d_in[0];
    const float* W    = (const float*)d_in[2];
    const float* U    = (const float*)d_in[3];
    const float* bias = (const float*)d_in[4];
    const float* wg   = (const float*)d_in[5];
    const float* bgam = (const float*)d_in[6];
    const float* wb   = (const float*)d_in[7];
    const float* bbet = (const float*)d_in[8];
    float* out = (float*)d_out;

    lstm_film_mfma<<<Bsz, 256, 0, stream>>>(x, W, U, bias,
                                            wg, bgam, wb, bbet, out);
}